// Round 7
// baseline (294.151 us; speedup 1.0000x reference)
//
#include <hip/hip_runtime.h>

typedef unsigned int u32;
typedef unsigned short u16;
typedef unsigned char u8;
typedef unsigned long long u64;

typedef __attribute__((ext_vector_type(8))) short bf16x8;
typedef __attribute__((ext_vector_type(4))) float f32x4;

#define L_SEQ 200

// Measured facts (R2..R6): float tensors are f32 storage; output is f32;
// MFMA 16x16x32_bf16 layouts verified in-situ (R6 pass, absmax 3.05e-5).
__device__ __forceinline__ u16 f2bf(float f) {
    u32 u = __float_as_uint(f);
    return (u16)((u + 0x7FFFu + ((u >> 16) & 1u)) >> 16);  // RNE
}
__device__ __forceinline__ float wave_sumf(float v) {
#pragma unroll
    for (int off = 32; off; off >>= 1) v += __shfl_xor(v, off, 64);
    return v;
}

// ---- single fused kernel: wave = 1 sample -----------------------------------
// A-frags: lane (col,g) loads emb row idx(l0+col) dims [g*8,+8) and [32+g*8,+8)
// from global as float4, RNE-packs to bf16. B-frags: tran_W staged once/block
// to LDS in B-frag order, hoisted into 96 VGPRs. C/D layout: col=lane&15,
// row=4*(lane>>4)+reg. Streaming no-max softmax (logits >= 0, bounded).
// x_mask encoding detected in-kernel from its first 800 bytes (wave-uniform).
__global__ __launch_bounds__(256, 4) void etna_mfma(
    const int* __restrict__ x, const void* __restrict__ xmask,
    const float* __restrict__ ob, const float* __restrict__ emb,
    const float* __restrict__ tranW, const float* __restrict__ tranb,
    const float* __restrict__ attW, const float* __restrict__ attb,
    const float* __restrict__ W0, const float* __restrict__ W1, const float* __restrict__ W2,
    float* __restrict__ out, int Vn) {
    __shared__ __align__(16) short Wst[12288];  // B-frags [a][c][kh][lane][8]
    __shared__ float repl[4][3][64];

    const int tid = threadIdx.x;
    const int wv = tid >> 6;
    const int lane = tid & 63;
    const int col = lane & 15;  // A row m / B+D col n
    const int g = lane >> 4;    // k-chunk / D row group
    const int b = blockIdx.x * 4 + wv;

    // stage tran_W -> B-frag layout: element j of frag (a,c,kh,lane) is
    // tranW[a][k = kh*32 + (lane>>4)*8 + j][n = c*16 + (lane&15)]
    for (int it = tid; it < 12288; it += 256) {
        int jj = it & 7;
        int ln = (it >> 3) & 63;
        int kh = (it >> 9) & 1;
        int c = (it >> 10) & 3;
        int a = it >> 12;
        int k = kh * 32 + (ln >> 4) * 8 + jj;
        int n = c * 16 + (ln & 15);
        Wst[it] = (short)f2bf(tranW[a * 4096 + k * 64 + n]);
    }
    __syncthreads();

    bf16x8 Bf[3][4][2];
#pragma unroll
    for (int a = 0; a < 3; ++a)
#pragma unroll
        for (int c = 0; c < 4; ++c)
#pragma unroll
            for (int kh = 0; kh < 2; ++kh)
                Bf[a][c][kh] = *(const bf16x8*)&Wst[(((a * 4 + c) * 2 + kh) * 64 + lane) * 8];

    // ---- in-kernel x_mask encoding detection (first 800 bytes, all-encoding
    // safe: min buffer is B*L*1 = 819200 bytes). Bytes of word i are offsets
    // 4i..4i+3. f32 true = [0,0,0x80,0x3F]; bf16 true = [0x80,0x3F]; u8 = [1];
    // i32 true = [1,0,0,0].
    int esz;
    {
        u32 accF = 0, acc0 = 0, accO = 0;
#pragma unroll
        for (int k = 0; k < 4; ++k) {
            int i = lane + 64 * k;
            u32 w = (i < 200) ? ((const u32*)xmask)[i] : 0u;
            accF |= (w & 0xFEFEFEFEu);  // any bits beyond bit0 -> float encoding
            acc0 |= (w & 0x000000FFu);  // nonzero byte at off%4==0 (float: bf16 only)
            accO |= (w & 0xFFFFFF00u);  // nonzero byte at off%4!=0 (int: u8 only)
        }
        bool isFloat = __ballot(accF != 0) != 0;
        bool hasB0   = __ballot(acc0 != 0) != 0;
        bool hasOdd  = __ballot(accO != 0) != 0;
        esz = isFloat ? (hasB0 ? 2 : 4) : (hasOdd ? 1 : 4);
    }

    // prefix length + preload all sequence indices (removes per-tile idx load
    // from the dependent chain; per-tile idx comes from a shuffle instead)
    int len = 0;
    int iv[4];
    const int* xrow = x + b * L_SEQ;
    {
        int mbase = b * L_SEQ;
#pragma unroll
        for (int c4 = 0; c4 < 4; ++c4) {
            int l = c4 * 64 + lane;
            bool v = false;
            if (l < L_SEQ) {
                int off = mbase + l;
                if (esz == 1)      v = ((const u8*)xmask)[off] != 0;
                else if (esz == 2) v = ((const u16*)xmask)[off] != 0;
                else               v = ((const u32*)xmask)[off] != 0;
            }
            iv[c4] = (l < L_SEQ) ? xrow[l] : 0;
            len += (int)__popcll(__ballot(v));
        }
    }

    // per-lane constants in C-layout (dim = c*16+col); attb is wave-uniform
    float TB[3][4], AW[3][4], AB[3];
#pragma unroll
    for (int a = 0; a < 3; ++a) {
#pragma unroll
        for (int c = 0; c < 4; ++c) {
            TB[a][c] = tranb[a * 64 + c * 16 + col];
            AW[a][c] = attW[a * 64 + c * 16 + col];
        }
        AB[a] = attb[a];
    }

    float NUM[3][4] = {{0.f}};
    float DEN[3] = {0.f, 0.f, 0.f};
    const float LOG2E = 1.44269504088896f;

    for (int l0 = 0; l0 < len; l0 += 16) {
        int p = l0 + col;
        int idx = __shfl(iv[p >> 6], p & 63, 64);
        idx = (p < len) ? idx : 0;           // emb row 0 is all zeros
        idx = max(0, min(idx, Vn - 1));      // defensive clamp
        const float4* ep4 = (const float4*)(emb + (size_t)idx * 64);
        float4 q0 = ep4[2 * g], q1 = ep4[2 * g + 1];      // dims g*8 .. g*8+7
        float4 q2 = ep4[8 + 2 * g], q3 = ep4[9 + 2 * g];  // dims 32+g*8 ..
        bf16x8 a0, a1;
        a0[0] = (short)f2bf(q0.x); a0[1] = (short)f2bf(q0.y);
        a0[2] = (short)f2bf(q0.z); a0[3] = (short)f2bf(q0.w);
        a0[4] = (short)f2bf(q1.x); a0[5] = (short)f2bf(q1.y);
        a0[6] = (short)f2bf(q1.z); a0[7] = (short)f2bf(q1.w);
        a1[0] = (short)f2bf(q2.x); a1[1] = (short)f2bf(q2.y);
        a1[2] = (short)f2bf(q2.z); a1[3] = (short)f2bf(q2.w);
        a1[4] = (short)f2bf(q3.x); a1[5] = (short)f2bf(q3.y);
        a1[6] = (short)f2bf(q3.z); a1[7] = (short)f2bf(q3.w);

#pragma unroll
        for (int a = 0; a < 3; ++a) {
            f32x4 E[4];
#pragma unroll
            for (int c = 0; c < 4; ++c) {
                f32x4 cc = {TB[a][c], TB[a][c], TB[a][c], TB[a][c]};
                cc = __builtin_amdgcn_mfma_f32_16x16x32_bf16(a0, Bf[a][c][0], cc, 0, 0, 0);
                cc = __builtin_amdgcn_mfma_f32_16x16x32_bf16(a1, Bf[a][c][1], cc, 0, 0, 0);
                E[c].x = fmaxf(cc.x, 0.f);
                E[c].y = fmaxf(cc.y, 0.f);
                E[c].z = fmaxf(cc.z, 0.f);
                E[c].w = fmaxf(cc.w, 0.f);
            }
            float p0 = E[0].x * AW[a][0] + E[1].x * AW[a][1] + E[2].x * AW[a][2] + E[3].x * AW[a][3];
            float p1 = E[0].y * AW[a][0] + E[1].y * AW[a][1] + E[2].y * AW[a][2] + E[3].y * AW[a][3];
            float p2 = E[0].z * AW[a][0] + E[1].z * AW[a][1] + E[2].z * AW[a][2] + E[3].z * AW[a][3];
            float p3 = E[0].w * AW[a][0] + E[1].w * AW[a][1] + E[2].w * AW[a][2] + E[3].w * AW[a][3];
#pragma unroll
            for (int off = 1; off <= 8; off <<= 1) {  // sum 16 cols in-group
                p0 += __shfl_xor(p0, off, 64);
                p1 += __shfl_xor(p1, off, 64);
                p2 += __shfl_xor(p2, off, 64);
                p3 += __shfl_xor(p3, off, 64);
            }
            int lrow = l0 + 4 * g;
            float u0 = fmaxf(p0 + AB[a], 0.f);
            float u1 = fmaxf(p1 + AB[a], 0.f);
            float u2 = fmaxf(p2 + AB[a], 0.f);
            float u3 = fmaxf(p3 + AB[a], 0.f);
            float s0 = (lrow + 0 < len) ? exp2f(u0 * LOG2E) : 0.f;
            float s1 = (lrow + 1 < len) ? exp2f(u1 * LOG2E) : 0.f;
            float s2 = (lrow + 2 < len) ? exp2f(u2 * LOG2E) : 0.f;
            float s3 = (lrow + 3 < len) ? exp2f(u3 * LOG2E) : 0.f;
            DEN[a] += s0 + s1 + s2 + s3;
#pragma unroll
            for (int c = 0; c < 4; ++c)
                NUM[a][c] += s0 * E[c].x + s1 * E[c].y + s2 * E[c].z + s3 * E[c].w;
        }
    }

    // fold the 4 row-groups; rep -> per-wave LDS (same-wave float/float pattern)
#pragma unroll
    for (int a = 0; a < 3; ++a) {
        float d = DEN[a];
        d += __shfl_xor(d, 16, 64);
        d += __shfl_xor(d, 32, 64);
        float rden = 1.0f / fmaxf(d, 1e-20f);  // den >= 1 when len >= 1
#pragma unroll
        for (int c = 0; c < 4; ++c) {
            float v = NUM[a][c];
            v += __shfl_xor(v, 16, 64);
            v += __shfl_xor(v, 32, 64);
            if (g == 0) repl[wv][a][c * 16 + col] = tanhf(v * rden);
        }
    }

    // epilogue: torch interleave u[3d+a]=rep[a][d]; segment s -> u[64s:64s+64]@Ws
    float outv = 0.f;
    {
        int gg = lane; float v = repl[wv][gg % 3][gg / 3];
#pragma unroll
        for (int k = 0; k < 2; ++k) {
            float p = wave_sumf(v * W0[lane * 2 + k]);
            if (lane == k) outv = p;
        }
    }
    {
        int gg = 64 + lane; float v = repl[wv][gg % 3][gg / 3];
#pragma unroll
        for (int k = 0; k < 6; ++k) {
            float p = wave_sumf(v * W1[lane * 6 + k]);
            if (lane == 2 + k) outv = p;
        }
    }
    {
        int gg = 128 + lane; float v = repl[wv][gg % 3][gg / 3];
#pragma unroll
        for (int k = 0; k < 10; ++k) {
            float p = wave_sumf(v * W2[lane * 10 + k]);
            if (lane == 8 + k) outv = p;
        }
    }
    if (lane < 18) out[b * 18 + lane] = outv * ob[b * 18 + lane];
}

extern "C" void kernel_launch(void* const* d_in, const int* in_sizes, int n_in,
                              void* d_out, int out_size, void* d_ws, size_t ws_size,
                              hipStream_t stream) {
    const int* x = (const int*)d_in[0];
    const void* xmask = d_in[1];
    // d_in[2] = y : unused
    const float* ob = (const float*)d_in[3];
    const float* emb = (const float*)d_in[4];
    const float* tranW = (const float*)d_in[5];
    const float* tranb = (const float*)d_in[6];
    const float* attW = (const float*)d_in[7];
    const float* attb = (const float*)d_in[8];
    const float* W0 = (const float*)d_in[9];
    const float* W1 = (const float*)d_in[10];
    const float* W2 = (const float*)d_in[11];

    const int Bn = in_sizes[0] / L_SEQ;  // 4096
    const int Vn = in_sizes[4] / 64;     // vocab rows

    etna_mfma<<<Bn / 4, 256, 0, stream>>>(x, xmask, ob, emb, tranW, tranb, attW, attb,
                                          W0, W1, W2, (float*)d_out, Vn);
}

// Round 8
// 171.557 us; speedup vs baseline: 1.7146x; 1.7146x over previous
//
#include <hip/hip_runtime.h>

typedef unsigned int u32;
typedef unsigned short u16;
typedef unsigned char u8;
typedef unsigned long long u64;

typedef __attribute__((ext_vector_type(8))) short bf16x8;
typedef __attribute__((ext_vector_type(4))) float f32x4;
typedef __attribute__((ext_vector_type(4))) u32 u32x4;

#define L_SEQ 200

// Measured facts: float tensors are f32 (R6); MFMA 16x16x32_bf16 A/B/C layouts
// verified (R6 pass, absmax 3.05e-5); launch_bounds(256,4) spills Bf -> 575 MB
// scratch traffic (R7) -- keep (256,2), VGPR ~120 => 4 waves/SIMD in HW.
__device__ __forceinline__ u16 f2bf(float f) {
    u32 u = __float_as_uint(f);
    return (u16)((u + 0x7FFFu + ((u >> 16) & 1u)) >> 16);  // RNE
}
// pack two f32 -> (bf16(y)<<16)|bf16(x), round-half-up (ties differ from RNE only)
__device__ __forceinline__ u32 pk2bf(float fx, float fy) {
    u32 xb = __float_as_uint(fx) + 0x8000u;
    u32 yb = __float_as_uint(fy) + 0x8000u;
    return __byte_perm(xb, yb, 0x7632);
}
__device__ __forceinline__ float wave_sumf(float v) {
#pragma unroll
    for (int off = 32; off; off >>= 1) v += __shfl_xor(v, off, 64);
    return v;
}

// ---- single fused kernel: wave = 1 sample -----------------------------------
// A-frags: lane (col,g) loads emb row idx(l0+col) dims [g*8,+8) and [32+g*8,+8)
// as float4, packs to bf16 via byte_perm. B-frags: tran_W staged once/block to
// LDS in B-frag order, hoisted to 96 VGPRs. C/D: col=lane&15, row=4*(lane>>4)+reg.
// Streaming no-max softmax (logits >= 0, bounded). Mask encoding detected
// in-kernel from its first 800 bytes (safe for all candidate widths).
__global__ __launch_bounds__(256, 2) void etna_mfma(
    const int* __restrict__ x, const void* __restrict__ xmask,
    const float* __restrict__ ob, const float* __restrict__ emb,
    const float* __restrict__ tranW, const float* __restrict__ tranb,
    const float* __restrict__ attW, const float* __restrict__ attb,
    const float* __restrict__ W0, const float* __restrict__ W1, const float* __restrict__ W2,
    float* __restrict__ out, int Vn) {
    __shared__ __align__(16) short Wst[12288];  // B-frags [a][c][kh][lane][8]
    __shared__ float repl[4][3][64];

    const int tid = threadIdx.x;
    const int wv = tid >> 6;
    const int lane = tid & 63;
    const int col = lane & 15;  // A row m / B+D col n
    const int g = lane >> 4;    // k-chunk / D row group
    const int b = blockIdx.x * 4 + wv;

    // stage tran_W -> B-frag layout: element j of frag (a,c,kh,lane) is
    // tranW[a][k = kh*32 + (lane>>4)*8 + j][n = c*16 + (lane&15)]
    for (int it = tid; it < 12288; it += 256) {
        int jj = it & 7;
        int ln = (it >> 3) & 63;
        int kh = (it >> 9) & 1;
        int c = (it >> 10) & 3;
        int a = it >> 12;
        int k = kh * 32 + (ln >> 4) * 8 + jj;
        int n = c * 16 + (ln & 15);
        Wst[it] = (short)f2bf(tranW[a * 4096 + k * 64 + n]);
    }
    __syncthreads();

    bf16x8 Bf[3][4][2];
#pragma unroll
    for (int a = 0; a < 3; ++a)
#pragma unroll
        for (int c = 0; c < 4; ++c)
#pragma unroll
            for (int kh = 0; kh < 2; ++kh)
                Bf[a][c][kh] = *(const bf16x8*)&Wst[(((a * 4 + c) * 2 + kh) * 64 + lane) * 8];

    // in-kernel x_mask encoding detection (first 800 bytes; len>=1 guarantees a
    // true element in range for every encoding). f32 true=[0,0,0x80,0x3F];
    // bf16=[0x80,0x3F]; u8=[1]; i32=[1,0,0,0].
    int esz;
    {
        u32 accF = 0, acc0 = 0, accO = 0;
#pragma unroll
        for (int k = 0; k < 4; ++k) {
            int i = lane + 64 * k;
            u32 w = (i < 200) ? ((const u32*)xmask)[i] : 0u;
            accF |= (w & 0xFEFEFEFEu);  // bits beyond bit0 -> float encoding
            acc0 |= (w & 0x000000FFu);  // nonzero byte at off%4==0 (float: bf16 only)
            accO |= (w & 0xFFFFFF00u);  // nonzero byte at off%4!=0 (int: u8 only)
        }
        bool isFloat = __ballot(accF != 0) != 0;
        bool hasB0   = __ballot(acc0 != 0) != 0;
        bool hasOdd  = __ballot(accO != 0) != 0;
        esz = isFloat ? (hasB0 ? 2 : 4) : (hasOdd ? 1 : 4);
    }

    // prefix length
    int len = 0;
    {
        int mbase = b * L_SEQ;
#pragma unroll
        for (int c4 = 0; c4 < 4; ++c4) {
            int l = c4 * 64 + lane;
            bool v = false;
            if (l < L_SEQ) {
                int off = mbase + l;
                if (esz == 1)      v = ((const u8*)xmask)[off] != 0;
                else if (esz == 2) v = ((const u16*)xmask)[off] != 0;
                else               v = ((const u32*)xmask)[off] != 0;
            }
            len += (int)__popcll(__ballot(v));
        }
    }

    // per-lane constants in C-layout (dim = c*16+col)
    float TB[3][4], AW[3][4], AB[3];
#pragma unroll
    for (int a = 0; a < 3; ++a) {
#pragma unroll
        for (int c = 0; c < 4; ++c) {
            TB[a][c] = tranb[a * 64 + c * 16 + col];
            AW[a][c] = attW[a * 64 + c * 16 + col];
        }
        AB[a] = attb[a];
    }

    float NUM[3][4] = {{0.f}};
    float DEN[3] = {0.f, 0.f, 0.f};
    const float LOG2E = 1.44269504088896f;
    const int* xrow = x + b * L_SEQ;

    for (int l0 = 0; l0 < len; l0 += 16) {
        int l = l0 + col;
        int idx = (l < len) ? xrow[l] : 0;   // emb row 0 is all zeros
        idx = max(0, min(idx, Vn - 1));      // defensive clamp
        const float4* ep4 = (const float4*)(emb + (size_t)idx * 64);
        float4 q0 = ep4[2 * g], q1 = ep4[2 * g + 1];      // dims g*8 .. g*8+7
        float4 q2 = ep4[8 + 2 * g], q3 = ep4[9 + 2 * g];  // dims 32+g*8 ..
        u32x4 r0, r1;
        r0.x = pk2bf(q0.x, q0.y); r0.y = pk2bf(q0.z, q0.w);
        r0.z = pk2bf(q1.x, q1.y); r0.w = pk2bf(q1.z, q1.w);
        r1.x = pk2bf(q2.x, q2.y); r1.y = pk2bf(q2.z, q2.w);
        r1.z = pk2bf(q3.x, q3.y); r1.w = pk2bf(q3.z, q3.w);
        bf16x8 a0 = __builtin_bit_cast(bf16x8, r0);
        bf16x8 a1 = __builtin_bit_cast(bf16x8, r1);

#pragma unroll
        for (int a = 0; a < 3; ++a) {
            f32x4 E[4];
#pragma unroll
            for (int c = 0; c < 4; ++c) {
                f32x4 cc = {TB[a][c], TB[a][c], TB[a][c], TB[a][c]};
                cc = __builtin_amdgcn_mfma_f32_16x16x32_bf16(a0, Bf[a][c][0], cc, 0, 0, 0);
                cc = __builtin_amdgcn_mfma_f32_16x16x32_bf16(a1, Bf[a][c][1], cc, 0, 0, 0);
                E[c].x = fmaxf(cc.x, 0.f);
                E[c].y = fmaxf(cc.y, 0.f);
                E[c].z = fmaxf(cc.z, 0.f);
                E[c].w = fmaxf(cc.w, 0.f);
            }
            float p0 = E[0].x * AW[a][0] + E[1].x * AW[a][1] + E[2].x * AW[a][2] + E[3].x * AW[a][3];
            float p1 = E[0].y * AW[a][0] + E[1].y * AW[a][1] + E[2].y * AW[a][2] + E[3].y * AW[a][3];
            float p2 = E[0].z * AW[a][0] + E[1].z * AW[a][1] + E[2].z * AW[a][2] + E[3].z * AW[a][3];
            float p3 = E[0].w * AW[a][0] + E[1].w * AW[a][1] + E[2].w * AW[a][2] + E[3].w * AW[a][3];
#pragma unroll
            for (int off = 1; off <= 8; off <<= 1) {  // sum 16 cols in-group
                p0 += __shfl_xor(p0, off, 64);
                p1 += __shfl_xor(p1, off, 64);
                p2 += __shfl_xor(p2, off, 64);
                p3 += __shfl_xor(p3, off, 64);
            }
            int lrow = l0 + 4 * g;
            float u0 = fmaxf(p0 + AB[a], 0.f);
            float u1 = fmaxf(p1 + AB[a], 0.f);
            float u2 = fmaxf(p2 + AB[a], 0.f);
            float u3 = fmaxf(p3 + AB[a], 0.f);
            float s0 = (lrow + 0 < len) ? exp2f(u0 * LOG2E) : 0.f;
            float s1 = (lrow + 1 < len) ? exp2f(u1 * LOG2E) : 0.f;
            float s2 = (lrow + 2 < len) ? exp2f(u2 * LOG2E) : 0.f;
            float s3 = (lrow + 3 < len) ? exp2f(u3 * LOG2E) : 0.f;
            DEN[a] += s0 + s1 + s2 + s3;
#pragma unroll
            for (int c = 0; c < 4; ++c)
                NUM[a][c] += s0 * E[c].x + s1 * E[c].y + s2 * E[c].z + s3 * E[c].w;
        }
    }

    // fold the 4 row-groups; rep -> per-wave LDS (same-wave float/float pattern)
#pragma unroll
    for (int a = 0; a < 3; ++a) {
        float d = DEN[a];
        d += __shfl_xor(d, 16, 64);
        d += __shfl_xor(d, 32, 64);
        float rden = 1.0f / fmaxf(d, 1e-20f);  // den >= 1 when len >= 1
#pragma unroll
        for (int c = 0; c < 4; ++c) {
            float v = NUM[a][c];
            v += __shfl_xor(v, 16, 64);
            v += __shfl_xor(v, 32, 64);
            if (g == 0) repl[wv][a][c * 16 + col] = tanhf(v * rden);
        }
    }

    // epilogue: torch interleave u[3d+a]=rep[a][d]; segment s -> u[64s:64s+64]@Ws
    float outv = 0.f;
    {
        int gg = lane; float v = repl[wv][gg % 3][gg / 3];
#pragma unroll
        for (int k = 0; k < 2; ++k) {
            float p = wave_sumf(v * W0[lane * 2 + k]);
            if (lane == k) outv = p;
        }
    }
    {
        int gg = 64 + lane; float v = repl[wv][gg % 3][gg / 3];
#pragma unroll
        for (int k = 0; k < 6; ++k) {
            float p = wave_sumf(v * W1[lane * 6 + k]);
            if (lane == 2 + k) outv = p;
        }
    }
    {
        int gg = 128 + lane; float v = repl[wv][gg % 3][gg / 3];
#pragma unroll
        for (int k = 0; k < 10; ++k) {
            float p = wave_sumf(v * W2[lane * 10 + k]);
            if (lane == 8 + k) outv = p;
        }
    }
    if (lane < 18) out[b * 18 + lane] = outv * ob[b * 18 + lane];
}

extern "C" void kernel_launch(void* const* d_in, const int* in_sizes, int n_in,
                              void* d_out, int out_size, void* d_ws, size_t ws_size,
                              hipStream_t stream) {
    const int* x = (const int*)d_in[0];
    const void* xmask = d_in[1];
    // d_in[2] = y : unused
    const float* ob = (const float*)d_in[3];
    const float* emb = (const float*)d_in[4];
    const float* tranW = (const float*)d_in[5];
    const float* tranb = (const float*)d_in[6];
    const float* attW = (const float*)d_in[7];
    const float* attb = (const float*)d_in[8];
    const float* W0 = (const float*)d_in[9];
    const float* W1 = (const float*)d_in[10];
    const float* W2 = (const float*)d_in[11];

    const int Bn = in_sizes[0] / L_SEQ;  // 4096
    const int Vn = in_sizes[4] / 64;     // vocab rows

    etna_mfma<<<Bn / 4, 256, 0, stream>>>(x, xmask, ob, emb, tranW, tranb, attW, attb,
                                          W0, W1, W2, (float*)d_out, Vn);
}